// Round 1
// baseline (354.249 us; speedup 1.0000x reference)
//
#include <hip/hip_runtime.h>

#define DIM  128
#define SREF 10
#define WREC 8   // recurrence window: dropped carry weighted 128^-8 ~ 1.4e-17 (below f32 ulp)

// ---------------- stats: per-dim mean / unbiased std, pre-folded -------------
// params layout (floats): [0:128) mu_n | [128:256) b_n | [256:384) c_n
//                         [384:512) mu_a | [512:640) b_a | [640:768) c_a
// b = -0.5/var, c = (1/sqrt(2pi))/sd  so pdf = c * exp(b*(x-mu)^2)
__global__ void stats_kernel(const float* __restrict__ nd,
                             const float* __restrict__ ad,
                             float* __restrict__ params) {
    int d = threadIdx.x;
    if (d >= DIM) return;
    const float INV_SQRT_2PI = 0.3989422804014327f;

    {
        float v[SREF]; float s = 0.f;
        #pragma unroll
        for (int j = 0; j < SREF; ++j) { v[j] = nd[d * SREF + j]; s += v[j]; }
        float mu = s * (1.0f / SREF);
        float var = 0.f;
        #pragma unroll
        for (int j = 0; j < SREF; ++j) { float t = v[j] - mu; var = fmaf(t, t, var); }
        var *= (1.0f / (SREF - 1));
        float sd = sqrtf(var);
        params[d]           = mu;
        params[DIM + d]     = -0.5f / var;
        params[2 * DIM + d] = INV_SQRT_2PI / sd;
    }
    {
        float v[SREF]; float s = 0.f;
        #pragma unroll
        for (int j = 0; j < SREF; ++j) { v[j] = ad[d * SREF + j]; s += v[j]; }
        float mu = s * (1.0f / SREF);
        float var = 0.f;
        #pragma unroll
        for (int j = 0; j < SREF; ++j) { float t = v[j] - mu; var = fmaf(t, t, var); }
        var *= (1.0f / (SREF - 1));
        float sd = sqrtf(var);
        params[3 * DIM + d] = mu;
        params[4 * DIM + d] = -0.5f / var;
        params[5 * DIM + d] = INV_SQRT_2PI / sd;
    }
}

// ---------------- score: 32 lanes per row, float4 loads ----------------------
__global__ __launch_bounds__(256) void score_kernel(const float* __restrict__ enc,
                                                    const float* __restrict__ params,
                                                    float2* __restrict__ s_out,
                                                    int n_rows) {
    const int lane = threadIdx.x & 31;
    const int row  = blockIdx.x * 8 + (threadIdx.x >> 5);

    const float4* p4 = (const float4*)params;   // 32 float4 per 128-float section
    const float4 mu_n = p4[       lane];
    const float4 b_n  = p4[ 32 +  lane];
    const float4 c_n  = p4[ 64 +  lane];
    const float4 mu_a = p4[ 96 +  lane];
    const float4 b_a  = p4[128 +  lane];
    const float4 c_a  = p4[160 +  lane];

    if (row >= n_rows) return;

    const float4 x = ((const float4*)enc)[row * 32 + lane];

    float sn = 0.f, sa = 0.f;
#define PDF_ACC(comp)                                                          \
    {                                                                          \
        float dn = x.comp - mu_n.comp;                                         \
        sn = fmaf(c_n.comp, __expf(b_n.comp * dn * dn), sn);                   \
        float da = x.comp - mu_a.comp;                                         \
        sa = fmaf(c_a.comp, __expf(b_a.comp * da * da), sa);                   \
    }
    PDF_ACC(x) PDF_ACC(y) PDF_ACC(z) PDF_ACC(w)
#undef PDF_ACC

    // reduce across the 32 lanes of this row
    #pragma unroll
    for (int m = 16; m >= 1; m >>= 1) {
        sn += __shfl_xor(sn, m, 32);
        sa += __shfl_xor(sa, m, 32);
    }
    if (lane == 0) s_out[row] = make_float2(sn, sa);
}

// ---------------- finalize: windowed scan + normalize ------------------------
__global__ __launch_bounds__(256) void finalize_kernel(const float2* __restrict__ s,
                                                       float2* __restrict__ out,
                                                       int n) {
    int i = blockIdx.x * blockDim.x + threadIdx.x;
    if (i >= n) return;
    const float inv_dim = 1.0f / 128.0f;
    float pn = 0.f, pa = 0.f;
    int k0 = i - (WREC - 1);
    if (k0 < 0) k0 = 0;
    for (int k = k0; k <= i; ++k) {   // replays reference rounding for last WREC steps
        float2 sv = s[k];
        pn = (pn + sv.x) * inv_dim;
        pa = (pa + sv.y) * inv_dim;
    }
    float tot = pn + pa;
    out[i] = make_float2(pn / tot, pa / tot);
}

extern "C" void kernel_launch(void* const* d_in, const int* in_sizes, int n_in,
                              void* d_out, int out_size, void* d_ws, size_t ws_size,
                              hipStream_t stream) {
    const float* enc = (const float*)d_in[0];
    const float* nd  = (const float*)d_in[1];
    const float* ad  = (const float*)d_in[2];
    const int n_rows = in_sizes[0] / DIM;

    float*  params = (float*)d_ws;
    float2* s_buf  = (float2*)((char*)d_ws + 6 * DIM * sizeof(float));  // 8B-aligned (3072B off)

    stats_kernel<<<1, DIM, 0, stream>>>(nd, ad, params);
    score_kernel<<<(n_rows + 7) / 8, 256, 0, stream>>>(enc, params, s_buf, n_rows);
    finalize_kernel<<<(n_rows + 255) / 256, 256, 0, stream>>>(s_buf, (float2*)d_out, n_rows);
}

// Round 2
// 345.584 us; speedup vs baseline: 1.0251x; 1.0251x over previous
//
#include <hip/hip_runtime.h>

#define DIM  128
#define SREF 10
#define ROWS_OUT 64   // output rows per block
#define NPASS 9       // 9 passes x 8 row-slots = 72 score rows, covering [base-7, base+64]
#define ROWS_CMP (NPASS * 8)

// One fused kernel:
//  phase 0: threads 0..127 compute per-dim stats (redundant per block, L2-fed)
//           params pre-folded: b = -0.5/var, c = (1/sqrt(2pi))/sd
//  phase B: 8 row-slots x 32 lanes compute summed-pdf scores for 72 rows
//           (own 64 + previous 7 + 1 spare), lane0 -> LDS
//  phase C: threads 0..63 replay the last 8 recurrence steps (carry beyond
//           8 steps weighs 128^-8 ~ 1.4e-17, below f32 ulp) and normalize.
__global__ __launch_bounds__(256) void fused_kernel(const float* __restrict__ enc,
                                                    const float* __restrict__ nd,
                                                    const float* __restrict__ ad,
                                                    float2* __restrict__ out,
                                                    int n) {
    __shared__ float4 p4[6 * 32];       // [mu_n | b_n | c_n | mu_a | b_a | c_a] x 128 floats
    __shared__ float2 sc[ROWS_CMP];

    const int tid = threadIdx.x;
    const float INV_SQRT_2PI = 0.3989422804014327f;

    // ---- phase 0: stats ----
    if (tid < DIM) {
        float* pf = (float*)p4;
        {
            float v[SREF]; float s = 0.f;
            #pragma unroll
            for (int j = 0; j < SREF; ++j) { v[j] = nd[tid * SREF + j]; s += v[j]; }
            float mu = s * (1.0f / SREF);
            float var = 0.f;
            #pragma unroll
            for (int j = 0; j < SREF; ++j) { float t = v[j] - mu; var = fmaf(t, t, var); }
            var *= (1.0f / (SREF - 1));
            pf[tid]           = mu;
            pf[DIM + tid]     = -0.5f / var;
            pf[2 * DIM + tid] = INV_SQRT_2PI / sqrtf(var);
        }
        {
            float v[SREF]; float s = 0.f;
            #pragma unroll
            for (int j = 0; j < SREF; ++j) { v[j] = ad[tid * SREF + j]; s += v[j]; }
            float mu = s * (1.0f / SREF);
            float var = 0.f;
            #pragma unroll
            for (int j = 0; j < SREF; ++j) { float t = v[j] - mu; var = fmaf(t, t, var); }
            var *= (1.0f / (SREF - 1));
            pf[3 * DIM + tid] = mu;
            pf[4 * DIM + tid] = -0.5f / var;
            pf[5 * DIM + tid] = INV_SQRT_2PI / sqrtf(var);
        }
    }
    __syncthreads();

    const int lane = tid & 31;
    const int slot = tid >> 5;
    const int base = blockIdx.x * ROWS_OUT;

    const float4 mu_n = p4[       lane];
    const float4 b_n  = p4[ 32 +  lane];
    const float4 c_n  = p4[ 64 +  lane];
    const float4 mu_a = p4[ 96 +  lane];
    const float4 b_a  = p4[128 +  lane];
    const float4 c_a  = p4[160 +  lane];

    // ---- phase B: scores for rows [base-7, base+64] ----
    #pragma unroll
    for (int p = 0; p < NPASS; ++p) {
        const int idx = p * 8 + slot;
        const long g = (long)base - 7 + idx;
        float sn = 0.f, sa = 0.f;
        if (g >= 0 && g < n) {
            const float4 x = ((const float4*)enc)[g * 32 + lane];
#define PDF_ACC(comp)                                                          \
            {                                                                  \
                float dn = x.comp - mu_n.comp;                                 \
                sn = fmaf(c_n.comp, __expf(b_n.comp * dn * dn), sn);           \
                float da = x.comp - mu_a.comp;                                 \
                sa = fmaf(c_a.comp, __expf(b_a.comp * da * da), sa);           \
            }
            PDF_ACC(x) PDF_ACC(y) PDF_ACC(z) PDF_ACC(w)
#undef PDF_ACC
        }
        #pragma unroll
        for (int m = 16; m >= 1; m >>= 1) {
            sn += __shfl_xor(sn, m, 32);
            sa += __shfl_xor(sa, m, 32);
        }
        if (lane == 0) sc[idx] = make_float2(sn, sa);
    }
    __syncthreads();

    // ---- phase C: windowed scan + normalize ----
    if (tid < ROWS_OUT) {
        const int r = base + tid;
        if (r < n) {
            const float inv_dim = 1.0f / 128.0f;
            float pn = 0.f, pa = 0.f;
            // sc[tid + k] holds s[r - 7 + k]; leading zero rows (r<7) reproduce
            // the reference's shorter window exactly (zeros are fixed points).
            #pragma unroll
            for (int k = 0; k < 8; ++k) {
                const float2 sv = sc[tid + k];
                pn = (pn + sv.x) * inv_dim;
                pa = (pa + sv.y) * inv_dim;
            }
            const float tot = pn + pa;
            out[r] = make_float2(pn / tot, pa / tot);
        }
    }
}

extern "C" void kernel_launch(void* const* d_in, const int* in_sizes, int n_in,
                              void* d_out, int out_size, void* d_ws, size_t ws_size,
                              hipStream_t stream) {
    const float* enc = (const float*)d_in[0];
    const float* nd  = (const float*)d_in[1];
    const float* ad  = (const float*)d_in[2];
    const int n_rows = in_sizes[0] / DIM;

    fused_kernel<<<(n_rows + ROWS_OUT - 1) / ROWS_OUT, 256, 0, stream>>>(
        enc, nd, ad, (float2*)d_out, n_rows);
}